// Round 8
// baseline (1687.891 us; speedup 1.0000x reference)
//
#include <hip/hip_runtime.h>

#define NN 131072   // nodes
#define NG 4096     // graphs
#define NE 524288   // edges

__device__ __forceinline__ float lrelu(float a){ return a>=0.f ? a : 0.2f*a; }

// ============================================================================
// pool_gemm: [pool(prev layer)] -> H = X @ W   (2 graphs = 64 rows per block)
// W read directly from global (L2-hot) -> no barriers in GEMM loop.
// ============================================================================
template<int K, int PMODE, int KSEL>
__global__ __launch_bounds__(256) void pool_gemm_kernel(
    const float* __restrict__ Xin, float* bufA, unsigned char* nmg,
    const float* __restrict__ stat,    // [0:128] mean, [128:256] rstd, [256:384] pw/||pw||
    const float* __restrict__ gamma, const float* __restrict__ beta,
    const float* __restrict__ Wg,      // K x 128
    float* zacc)
{
    constexpr int XP = (K == 41) ? 44 : 132;   // padded LDS pitch (16B-aligned)
    __shared__ float xs[64 * XP];
    __shared__ float scS[64], tsS[64];
    __shared__ int   nmlS[64];

    int tid = threadIdx.x;
    long row0 = (long)blockIdx.x * 64;
    int g0 = blockIdx.x * 2;

    if (PMODE == 0) {
        for (int i = tid; i < 64 * 41; i += 256) {
            int r = i / 41, c = i - r * 41;
            xs[r * 44 + c] = Xin[row0 * 41 + i];
        }
    } else {
        for (int i = tid; i < 2048; i += 256) {
            int r = i >> 5, dc = (i & 31) * 4;
            float4 v = *(const float4*)&bufA[(row0 + r) * 128 + dc];
            v.x = fmaxf(gamma[dc    ] * (v.x - stat[dc    ]) * stat[128 + dc    ] + beta[dc    ], 0.f);
            v.y = fmaxf(gamma[dc + 1] * (v.y - stat[dc + 1]) * stat[128 + dc + 1] + beta[dc + 1], 0.f);
            v.z = fmaxf(gamma[dc + 2] * (v.z - stat[dc + 2]) * stat[128 + dc + 2] + beta[dc + 2], 0.f);
            v.w = fmaxf(gamma[dc + 3] * (v.w - stat[dc + 3]) * stat[128 + dc + 3] + beta[dc + 3], 0.f);
            *(float4*)&xs[r * XP + dc] = v;
        }
        if (tid < 64) nmlS[tid] = (PMODE == 1) ? 1 : (int)nmg[g0 * 32 + tid];
    }
    __syncthreads();

    if (PMODE > 0) {
        {   // pool scores
            int node = tid >> 2, l4 = tid & 3;
            float s = 0.f;
            for (int m = 0; m < 32; m++) { int c = l4 + 4 * m; s += xs[node * XP + c] * stat[256 + c]; }
            s += __shfl_xor(s, 2); s += __shfl_xor(s, 1);
            if (l4 == 0) scS[node] = s;
        }
        __syncthreads();
        if (tid < 64) {   // stable top-k (ties: lower index wins)
            int gp = tid >> 5, n = tid & 31;
            float sn = nmlS[tid] ? scS[tid] : -1e9f;
            int cnt = 0;
            for (int j = 0; j < 32; j++) {
                float sj = nmlS[gp * 32 + j] ? scS[gp * 32 + j] : -1e9f;
                cnt += (sj > sn || (sj == sn && j < n)) ? 1 : 0;
            }
            int sl = (cnt < KSEL) ? 1 : 0;
            nmg[g0 * 32 + tid] = (unsigned char)sl;
            tsS[tid] = sl ? tanhf(scS[tid]) : 0.f;
        }
        __syncthreads();
        for (int i = tid; i < 2048; i += 256) {   // gate
            int r = i >> 5, dc = (i & 31) * 4;
            float t = tsS[r];
            float4 v = *(const float4*)&xs[r * XP + dc];
            v.x *= t; v.y *= t; v.z *= t; v.w *= t;
            *(float4*)&xs[r * XP + dc] = v;
        }
        __syncthreads();
        {   // readout accumulation (block owns its 2 graphs)
            int gp = tid >> 7, d = tid & 127;
            float s = 0.f;
            for (int n = 0; n < 32; n++) s += xs[(gp * 32 + n) * XP + d];
            zacc[(long)(g0 + gp) * 128 + d] += s * (1.0f / (float)KSEL);
        }
        __syncthreads();
    }

    // ---- GEMM
    int r0 = (tid >> 5) * 8, c4 = (tid & 31) * 4;
    float acc[8][4];
#pragma unroll
    for (int i = 0; i < 8; i++)
#pragma unroll
        for (int j = 0; j < 4; j++) acc[i][j] = 0.f;

    constexpr int KM4 = (K / 4) * 4;
#pragma unroll 2
    for (int k0 = 0; k0 < KM4; k0 += 4) {
        float4 wv0 = *(const float4*)&Wg[(k0 + 0) * 128 + c4];
        float4 wv1 = *(const float4*)&Wg[(k0 + 1) * 128 + c4];
        float4 wv2 = *(const float4*)&Wg[(k0 + 2) * 128 + c4];
        float4 wv3 = *(const float4*)&Wg[(k0 + 3) * 128 + c4];
#pragma unroll
        for (int i = 0; i < 8; i++) {
            float4 xv = *(const float4*)&xs[(r0 + i) * XP + k0];
            acc[i][0] += xv.x * wv0.x + xv.y * wv1.x + xv.z * wv2.x + xv.w * wv3.x;
            acc[i][1] += xv.x * wv0.y + xv.y * wv1.y + xv.z * wv2.y + xv.w * wv3.y;
            acc[i][2] += xv.x * wv0.z + xv.y * wv1.z + xv.z * wv2.z + xv.w * wv3.z;
            acc[i][3] += xv.x * wv0.w + xv.y * wv1.w + xv.z * wv2.w + xv.w * wv3.w;
        }
    }
    for (int k = KM4; k < K; k++) {
        float4 wv = *(const float4*)&Wg[k * 128 + c4];
#pragma unroll
        for (int i = 0; i < 8; i++) {
            float xv = xs[(r0 + i) * XP + k];
            acc[i][0] += xv * wv.x; acc[i][1] += xv * wv.y;
            acc[i][2] += xv * wv.z; acc[i][3] += xv * wv.w;
        }
    }
#pragma unroll
    for (int i = 0; i < 8; i++)
        *(float4*)&bufA[(row0 + r0 + i) * 128 + c4] =
            make_float4(acc[i][0], acc[i][1], acc[i][2], acc[i][3]);
}

// ============================================================================
// attn: R4 skeleton (broadcast scans for max/den, FP-CAS scatter into dense
// Wm) + vectorized 4n x 4d float4 aggregation with 1/den folded in epilogue.
// ============================================================================
__global__ __launch_bounds__(256) void attn_kernel(
    float* bufA,
    const int* __restrict__ srcp, const int* __restrict__ dstp,
    const float* __restrict__ EA,
    const unsigned char* __restrict__ nmg,
    const float* __restrict__ stat,      // ve at [384:404]
    const float* __restrict__ as_, const float* __restrict__ ad_,
    const float* __restrict__ bb,
    float* sums)
{
    __shared__ float hs[32 * 132];       // 16.9 KB
    __shared__ float Wm[2 * 32 * 40];    // 10.2 KB, [h][src][dst] padded, UNNORMALIZED p
    __shared__ float alpha[256];         // [e][h]
    __shared__ float aself[64], hsd[64], hdd[64], lsumS[64], mxS[64], rdenS[64];
    __shared__ int   ldeS[128], lcntS[32], nmlS[32];

    int g = blockIdx.x, tid = threadIdx.x;
    long gb = (long)g * 4096;

    // ---- A: init + loads
    for (int i = tid; i < 2560; i += 256) Wm[i] = 0.f;
    if (tid < 64) lsumS[tid] = 0.f;
    if (tid >= 64 && tid < 96) { lcntS[tid - 64] = 0; nmlS[tid - 64] = (int)nmg[g * 32 + tid - 64]; }
    for (int i = tid; i < 1024; i += 256) {
        int r = i >> 5, dc = (i & 31) * 4;
        *(float4*)&hs[r * 132 + dc] = *(const float4*)&bufA[gb + i * 4];
    }
    float ea0 = 0.f, ea1 = 0.f;
    int myls = 0, myld = 0;
    if (tid < 128) {
        myls = srcp[g * 128 + tid] & 31;
        myld = dstp[g * 128 + tid] & 31;
        ldeS[tid] = myld;
        const float* ep = EA + (long)(g * 128 + tid) * 10;
#pragma unroll
        for (int j = 0; j < 10; j++) { float v = ep[j]; ea0 += v * stat[384 + j]; ea1 += v * stat[394 + j]; }
    }
    __syncthreads();   // B1

    // ---- B: node dots + loop-attr sums (FP CAS on 32 addrs — proven fast in R4)
    {
        int node = tid >> 3, l8 = tid & 7;
        float s0 = 0, s1 = 0, d0 = 0, d1 = 0;
        for (int m = 0; m < 8; m++) {
            int c = l8 + 8 * m;
            float h0 = hs[node * 132 + c], h1 = hs[node * 132 + 64 + c];
            s0 += h0 * as_[c]; s1 += h1 * as_[64 + c];
            d0 += h0 * ad_[c]; d1 += h1 * ad_[64 + c];
        }
        s0 += __shfl_xor(s0, 4); s0 += __shfl_xor(s0, 2); s0 += __shfl_xor(s0, 1);
        s1 += __shfl_xor(s1, 4); s1 += __shfl_xor(s1, 2); s1 += __shfl_xor(s1, 1);
        d0 += __shfl_xor(d0, 4); d0 += __shfl_xor(d0, 2); d0 += __shfl_xor(d0, 1);
        d1 += __shfl_xor(d1, 4); d1 += __shfl_xor(d1, 2); d1 += __shfl_xor(d1, 1);
        if (l8 == 0) { hsd[node * 2] = s0; hsd[node * 2 + 1] = s1; hdd[node * 2] = d0; hdd[node * 2 + 1] = d1; }
    }
    int mymk = 0;
    if (tid < 128) {
        mymk = nmlS[myls] & nmlS[myld];
        if (mymk) {
            atomicAdd(&lsumS[myld * 2], ea0);
            atomicAdd(&lsumS[myld * 2 + 1], ea1);
            atomicAdd(&lcntS[myld], 1);
        }
    }
    __syncthreads();   // B2

    // ---- C: edge alphas (regs + LDS) and self alphas
    float a0 = -1e9f, a1 = -1e9f;
    if (tid < 128) {
        if (mymk) {
            a0 = lrelu(hsd[myls * 2] + hdd[myld * 2] + ea0);
            a1 = lrelu(hsd[myls * 2 + 1] + hdd[myld * 2 + 1] + ea1);
        }
        alpha[tid * 2] = a0; alpha[tid * 2 + 1] = a1;
    } else if (tid < 160) {
        int n = tid - 128;
        float c = (lcntS[n] > 0) ? (float)lcntS[n] : 1.f;
#pragma unroll
        for (int h = 0; h < 2; h++) {
            float a = hsd[n * 2 + h] + hdd[n * 2 + h] + lsumS[n * 2 + h] / c;
            aself[n * 2 + h] = nmlS[n] ? lrelu(a) : -1e9f;
        }
    }
    __syncthreads();   // B3

    // ---- D: segment max + denominator via broadcast scans (n,h,half);
    //         self exp goes straight into the Wm diagonal (exclusive writer)
    if (tid < 128) {
        int n = tid >> 2, h = (tid >> 1) & 1, hf = tid & 1;
        float av = aself[n * 2 + h];
        float m = av;
        for (int e = hf * 64; e < hf * 64 + 64; e++)
            if (ldeS[e] == n) m = fmaxf(m, alpha[e * 2 + h]);
        m = fmaxf(m, __shfl_xor(m, 1));
        float s = 0.f;
        if (hf == 0 && av > -1e8f) {
            float ps = __expf(av - m);
            s = ps;
            Wm[h * 1280 + n * 40 + n] = ps;   // plain store; edge atomics add later
        }
        for (int e = hf * 64; e < hf * 64 + 64; e++)
            if (ldeS[e] == n) { float a = alpha[e * 2 + h]; if (a > -1e8f) s += __expf(a - m); }
        s += __shfl_xor(s, 1);
        if (hf == 0) { mxS[n * 2 + h] = m; rdenS[n * 2 + h] = 1.f / fmaxf(s, 1e-16f); }
    }
    __syncthreads();   // B4

    // ---- E: scatter unnormalized exp into dense Wm (FP CAS, low dupes)
    if (tid < 128 && mymk) {
        float p0 = __expf(a0 - mxS[myld * 2]);
        float p1 = __expf(a1 - mxS[myld * 2 + 1]);
        atomicAdd(&Wm[myls * 40 + myld], p0);
        atomicAdd(&Wm[1280 + myls * 40 + myld], p1);
    }
    __syncthreads();   // B5

    // ---- F: vector aggregation (4n x 4d float4 tile) + epilogue
    {
        int n0 = (tid & 7) * 4, d0 = (tid >> 3) * 4;
        int h = d0 >> 6;
        const float* WmH = &Wm[h * 1280];
        float acc[4][4];
#pragma unroll
        for (int i = 0; i < 4; i++)
#pragma unroll
            for (int j = 0; j < 4; j++) acc[i][j] = 0.f;
#pragma unroll 4
        for (int s = 0; s < 32; s++) {
            float4 hv = *(const float4*)&hs[s * 132 + d0];
            float4 wv = *(const float4*)&WmH[s * 40 + n0];
            acc[0][0] += wv.x * hv.x; acc[0][1] += wv.x * hv.y; acc[0][2] += wv.x * hv.z; acc[0][3] += wv.x * hv.w;
            acc[1][0] += wv.y * hv.x; acc[1][1] += wv.y * hv.y; acc[1][2] += wv.y * hv.z; acc[1][3] += wv.y * hv.w;
            acc[2][0] += wv.z * hv.x; acc[2][1] += wv.z * hv.y; acc[2][2] += wv.z * hv.z; acc[2][3] += wv.z * hv.w;
            acc[3][0] += wv.w * hv.x; acc[3][1] += wv.w * hv.y; acc[3][2] += wv.w * hv.z; acc[3][3] += wv.w * hv.w;
        }
        float4 bv = *(const float4*)&bb[d0];
        float sp[4] = {0, 0, 0, 0}, sq[4] = {0, 0, 0, 0};
#pragma unroll
        for (int ni = 0; ni < 4; ni++) {
            int n = n0 + ni;
            float rd = rdenS[n * 2 + h];
            float4 o;
            o.x = acc[ni][0] * rd + bv.x;
            o.y = acc[ni][1] * rd + bv.y;
            o.z = acc[ni][2] * rd + bv.z;
            o.w = acc[ni][3] * rd + bv.w;
            *(float4*)&bufA[gb + n * 128 + d0] = o;
            if (nmlS[n]) {
                sp[0] += o.x; sq[0] += o.x * o.x;
                sp[1] += o.y; sq[1] += o.y * o.y;
                sp[2] += o.z; sq[2] += o.z * o.z;
                sp[3] += o.w; sq[3] += o.w * o.w;
            }
        }
#pragma unroll
        for (int j = 0; j < 4; j++) {
            sp[j] += __shfl_xor(sp[j], 1); sp[j] += __shfl_xor(sp[j], 2); sp[j] += __shfl_xor(sp[j], 4);
            sq[j] += __shfl_xor(sq[j], 1); sq[j] += __shfl_xor(sq[j], 2); sq[j] += __shfl_xor(sq[j], 4);
        }
        if ((tid & 7) == 0) {
#pragma unroll
            for (int j = 0; j < 4; j++) {
                atomicAdd(&sums[d0 + j], sp[j]);
                atomicAdd(&sums[128 + d0 + j], sq[j]);
            }
        }
    }
}

// ============================================================================
__global__ __launch_bounds__(128) void setup_kernel(
    float* sums, float* stat, const float* __restrict__ We, const float* __restrict__ ae)
{
    int t = threadIdx.x;
    sums[t] = 0.f; sums[128 + t] = 0.f;
    if (t < 20) {
        int h = t / 10, j = t - 10 * h;
        float s = 0.f;
        for (int c = 0; c < 64; c++) s += We[j * 128 + h * 64 + c] * ae[h * 64 + c];
        stat[384 + t] = s;
    }
}

__global__ __launch_bounds__(128) void finalize_kernel(
    float* sums, float n, const float* __restrict__ pw, float* stat,
    const float* __restrict__ Wen, const float* __restrict__ aen)
{
    int d = threadIdx.x;
    float mean = sums[d] / n;
    float var = sums[128 + d] / n - mean * mean;
    if (var < 0.f) var = 0.f;
    float rstd = rsqrtf(var + 1e-5f);
    float p = pw[d];
    float q = p * p;
#pragma unroll
    for (int o = 32; o >= 1; o >>= 1) q += __shfl_xor(q, o);
    __shared__ float w2[2];
    if ((d & 63) == 0) w2[d >> 6] = q;
    __syncthreads();
    float nrm = sqrtf(w2[0] + w2[1]);
    stat[d] = mean; stat[128 + d] = rstd; stat[256 + d] = p / nrm;
    if (d < 20) {
        int h = d / 10, j = d - 10 * h;
        float s = 0.f;
        for (int c = 0; c < 64; c++) s += Wen[j * 128 + h * 64 + c] * aen[h * 64 + c];
        stat[384 + d] = s;
    }
    sums[d] = 0.f; sums[128 + d] = 0.f;
}

// ============================================================================
// final: pool layer-2 output (K=25) + readout + MLP head
// ============================================================================
__global__ __launch_bounds__(256) void final_kernel(
    const float* __restrict__ bufA, const unsigned char* __restrict__ nmg,
    const float* __restrict__ stat,
    const float* __restrict__ gamma, const float* __restrict__ beta,
    const float* __restrict__ zacc,
    const float* __restrict__ fw1, const float* __restrict__ fb1,
    const float* __restrict__ fw2, const float* __restrict__ fb2,
    float* __restrict__ out)
{
    __shared__ float xs[32 * 132], zt[128], hred[64], scS[32], tsS[32];
    __shared__ int nmlS[32];
    int g = blockIdx.x, tid = threadIdx.x;
    long gb = (long)g * 4096;

    if (tid < 32) nmlS[tid] = (int)nmg[g * 32 + tid];
    for (int i = tid; i < 1024; i += 256) {
        int r = i >> 5, dc = (i & 31) * 4;
        float4 v = *(const float4*)&bufA[gb + i * 4];
        v.x = fmaxf(gamma[dc    ] * (v.x - stat[dc    ]) * stat[128 + dc    ] + beta[dc    ], 0.f);
        v.y = fmaxf(gamma[dc + 1] * (v.y - stat[dc + 1]) * stat[128 + dc + 1] + beta[dc + 1], 0.f);
        v.z = fmaxf(gamma[dc + 2] * (v.z - stat[dc + 2]) * stat[128 + dc + 2] + beta[dc + 2], 0.f);
        v.w = fmaxf(gamma[dc + 3] * (v.w - stat[dc + 3]) * stat[128 + dc + 3] + beta[dc + 3], 0.f);
        *(float4*)&xs[r * 132 + dc] = v;
    }
    __syncthreads();

    {
        int node = tid >> 3, l8 = tid & 7;
        float s = 0.f;
        for (int m = 0; m < 16; m++) { int c = l8 + 8 * m; s += xs[node * 132 + c] * stat[256 + c]; }
        s += __shfl_xor(s, 4); s += __shfl_xor(s, 2); s += __shfl_xor(s, 1);
        if (l8 == 0) scS[node] = s;
    }
    __syncthreads();

    if (tid < 32) {
        float sn = nmlS[tid] ? scS[tid] : -1e9f;
        int cnt = 0;
        for (int j = 0; j < 32; j++) {
            float sj = nmlS[j] ? scS[j] : -1e9f;
            cnt += (sj > sn || (sj == sn && j < tid)) ? 1 : 0;
        }
        tsS[tid] = (cnt < 25) ? tanhf(scS[tid]) : 0.f;
    }
    __syncthreads();

    if (tid < 128) {
        float s = 0.f;
        for (int n = 0; n < 32; n++) s += xs[n * 132 + tid] * tsS[n];
        zt[tid] = zacc[(long)g * 128 + tid] + s * (1.0f / 25.0f);
    }
    __syncthreads();

    {
        int j = tid >> 2, p = tid & 3;
        float s = 0.f;
        for (int d = p * 32; d < p * 32 + 32; d++) s += zt[d] * fw1[d * 64 + j];
        s += __shfl_xor(s, 1); s += __shfl_xor(s, 2);
        if (p == 0) hred[j] = fmaxf(s + fb1[j], 0.f) * fw2[j];
    }
    __syncthreads();
    if (tid < 64) {
        float v = hred[tid];
#pragma unroll
        for (int o = 32; o >= 1; o >>= 1) v += __shfl_xor(v, o);
        if (tid == 0) out[g] = v + fb2[0];
    }
}

extern "C" void kernel_launch(void* const* d_in, const int* in_sizes, int n_in,
                              void* d_out, int out_size, void* d_ws, size_t ws_size,
                              hipStream_t stream)
{
    const float* X0 = (const float*)d_in[0];
    const int*   EI = (const int*)d_in[1];
    const float* EA = (const float*)d_in[2];
    const int* srcp = EI;
    const int* dstp = EI + NE;

    const float* W1  = (const float*)d_in[4];  const float* We1 = (const float*)d_in[5];
    const float* as1 = (const float*)d_in[6];  const float* ad1 = (const float*)d_in[7];
    const float* ae1 = (const float*)d_in[8];  const float* b1  = (const float*)d_in[9];
    const float* g1  = (const float*)d_in[10]; const float* be1 = (const float*)d_in[11];
    const float* pw1 = (const float*)d_in[12];
    const float* W2  = (const float*)d_in[13]; const float* We2 = (const float*)d_in[14];
    const float* as2 = (const float*)d_in[15]; const float* ad2 = (const float*)d_in[16];
    const float* ae2 = (const float*)d_in[17]; const float* b2  = (const float*)d_in[18];
    const float* g2  = (const float*)d_in[19]; const float* be2 = (const float*)d_in[20];
    const float* pw2 = (const float*)d_in[21];
    const float* W3  = (const float*)d_in[22]; const float* We3 = (const float*)d_in[23];
    const float* as3 = (const float*)d_in[24]; const float* ad3 = (const float*)d_in[25];
    const float* ae3 = (const float*)d_in[26]; const float* b3  = (const float*)d_in[27];
    const float* g3  = (const float*)d_in[28]; const float* be3 = (const float*)d_in[29];
    const float* pw3 = (const float*)d_in[30];
    const float* fw1 = (const float*)d_in[31]; const float* fb1 = (const float*)d_in[32];
    const float* fw2 = (const float*)d_in[33]; const float* fb2 = (const float*)d_in[34];

    float* bufA = (float*)d_ws;                       // NN*128 f32
    float* z    = bufA + (size_t)NN * 128;            // NG*128 f32
    float* sums = z + (size_t)NG * 128;               // 256 f32
    float* stat = sums + 256;                         // 512 f32
    unsigned char* nmg = (unsigned char*)(stat + 512);// NG*32 bytes

    hipMemsetAsync(nmg, 1, NN, stream);
    hipMemsetAsync(z, 0, (size_t)NG * 128 * sizeof(float), stream);
    setup_kernel<<<1, 128, 0, stream>>>(sums, stat, We1, ae1);

    // layer 0
    pool_gemm_kernel<41, 0, 1><<<NN / 64, 256, 0, stream>>>(
        X0, bufA, nmg, stat, g1, be1, W1, z);
    attn_kernel<<<NG, 256, 0, stream>>>(bufA, srcp, dstp, EA, nmg, stat, as1, ad1, b1, sums);
    finalize_kernel<<<1, 128, 0, stream>>>(sums, 131072.f, pw1, stat, We2, ae2);

    // layer 1 (pools layer-0 output, K=29)
    pool_gemm_kernel<128, 1, 29><<<NN / 64, 256, 0, stream>>>(
        X0, bufA, nmg, stat, g1, be1, W2, z);
    attn_kernel<<<NG, 256, 0, stream>>>(bufA, srcp, dstp, EA, nmg, stat, as2, ad2, b2, sums);
    finalize_kernel<<<1, 128, 0, stream>>>(sums, 4096.f * 29.f, pw2, stat, We3, ae3);

    // layer 2 (pools layer-1 output, K=27)
    pool_gemm_kernel<128, 2, 27><<<NN / 64, 256, 0, stream>>>(
        X0, bufA, nmg, stat, g2, be2, W3, z);
    attn_kernel<<<NG, 256, 0, stream>>>(bufA, srcp, dstp, EA, nmg, stat, as3, ad3, b3, sums);
    finalize_kernel<<<1, 128, 0, stream>>>(sums, 4096.f * 27.f, pw3, stat, We3, ae3);

    // final: pool layer-2 output (K=25) + readout + head
    final_kernel<<<NG, 256, 0, stream>>>(
        bufA, nmg, stat, g3, be3, z, fw1, fb1, fw2, fb2, (float*)d_out);
}

// Round 9
// 806.090 us; speedup vs baseline: 2.0939x; 2.0939x over previous
//
#include <hip/hip_runtime.h>

#define NN 131072   // nodes
#define NG 4096     // graphs
#define NE 524288   // edges

__device__ __forceinline__ float lrelu(float a){ return a>=0.f ? a : 0.2f*a; }

// ============================================================================
// pool_gemm: [pool(prev layer)] -> H = X @ W   (2 graphs = 64 rows per block)
// W read directly from global (L2-hot) -> no barriers in GEMM loop.
// ============================================================================
template<int K, int PMODE, int KSEL>
__global__ __launch_bounds__(256) void pool_gemm_kernel(
    const float* __restrict__ Xin, float* bufA, unsigned char* nmg,
    const float* __restrict__ stat,    // [0:128] mean, [128:256] rstd, [256:384] pw/||pw||
    const float* __restrict__ gamma, const float* __restrict__ beta,
    const float* __restrict__ Wg,      // K x 128
    float* zacc)
{
    constexpr int XP = (K == 41) ? 44 : 132;   // padded LDS pitch (16B-aligned)
    __shared__ float xs[64 * XP];
    __shared__ float scS[64], tsS[64];
    __shared__ int   nmlS[64];

    int tid = threadIdx.x;
    long row0 = (long)blockIdx.x * 64;
    int g0 = blockIdx.x * 2;

    if (PMODE == 0) {
        for (int i = tid; i < 64 * 41; i += 256) {
            int r = i / 41, c = i - r * 41;
            xs[r * 44 + c] = Xin[row0 * 41 + i];
        }
    } else {
        for (int i = tid; i < 2048; i += 256) {
            int r = i >> 5, dc = (i & 31) * 4;
            float4 v = *(const float4*)&bufA[(row0 + r) * 128 + dc];
            v.x = fmaxf(gamma[dc    ] * (v.x - stat[dc    ]) * stat[128 + dc    ] + beta[dc    ], 0.f);
            v.y = fmaxf(gamma[dc + 1] * (v.y - stat[dc + 1]) * stat[128 + dc + 1] + beta[dc + 1], 0.f);
            v.z = fmaxf(gamma[dc + 2] * (v.z - stat[dc + 2]) * stat[128 + dc + 2] + beta[dc + 2], 0.f);
            v.w = fmaxf(gamma[dc + 3] * (v.w - stat[dc + 3]) * stat[128 + dc + 3] + beta[dc + 3], 0.f);
            *(float4*)&xs[r * XP + dc] = v;
        }
        if (tid < 64) nmlS[tid] = (PMODE == 1) ? 1 : (int)nmg[g0 * 32 + tid];
    }
    __syncthreads();

    if (PMODE > 0) {
        {   // pool scores
            int node = tid >> 2, l4 = tid & 3;
            float s = 0.f;
            for (int m = 0; m < 32; m++) { int c = l4 + 4 * m; s += xs[node * XP + c] * stat[256 + c]; }
            s += __shfl_xor(s, 2); s += __shfl_xor(s, 1);
            if (l4 == 0) scS[node] = s;
        }
        __syncthreads();
        if (tid < 64) {   // stable top-k (ties: lower index wins)
            int gp = tid >> 5, n = tid & 31;
            float sn = nmlS[tid] ? scS[tid] : -1e9f;
            int cnt = 0;
            for (int j = 0; j < 32; j++) {
                float sj = nmlS[gp * 32 + j] ? scS[gp * 32 + j] : -1e9f;
                cnt += (sj > sn || (sj == sn && j < n)) ? 1 : 0;
            }
            int sl = (cnt < KSEL) ? 1 : 0;
            nmg[g0 * 32 + tid] = (unsigned char)sl;
            tsS[tid] = sl ? tanhf(scS[tid]) : 0.f;
        }
        __syncthreads();
        for (int i = tid; i < 2048; i += 256) {   // gate
            int r = i >> 5, dc = (i & 31) * 4;
            float t = tsS[r];
            float4 v = *(const float4*)&xs[r * XP + dc];
            v.x *= t; v.y *= t; v.z *= t; v.w *= t;
            *(float4*)&xs[r * XP + dc] = v;
        }
        __syncthreads();
        {   // readout accumulation (block owns its 2 graphs)
            int gp = tid >> 7, d = tid & 127;
            float s = 0.f;
            for (int n = 0; n < 32; n++) s += xs[(gp * 32 + n) * XP + d];
            zacc[(long)(g0 + gp) * 128 + d] += s * (1.0f / (float)KSEL);
        }
        __syncthreads();
    }

    // ---- GEMM
    int r0 = (tid >> 5) * 8, c4 = (tid & 31) * 4;
    float acc[8][4];
#pragma unroll
    for (int i = 0; i < 8; i++)
#pragma unroll
        for (int j = 0; j < 4; j++) acc[i][j] = 0.f;

    constexpr int KM4 = (K / 4) * 4;
#pragma unroll 2
    for (int k0 = 0; k0 < KM4; k0 += 4) {
        float4 wv0 = *(const float4*)&Wg[(k0 + 0) * 128 + c4];
        float4 wv1 = *(const float4*)&Wg[(k0 + 1) * 128 + c4];
        float4 wv2 = *(const float4*)&Wg[(k0 + 2) * 128 + c4];
        float4 wv3 = *(const float4*)&Wg[(k0 + 3) * 128 + c4];
#pragma unroll
        for (int i = 0; i < 8; i++) {
            float4 xv = *(const float4*)&xs[(r0 + i) * XP + k0];
            acc[i][0] += xv.x * wv0.x + xv.y * wv1.x + xv.z * wv2.x + xv.w * wv3.x;
            acc[i][1] += xv.x * wv0.y + xv.y * wv1.y + xv.z * wv2.y + xv.w * wv3.y;
            acc[i][2] += xv.x * wv0.z + xv.y * wv1.z + xv.z * wv2.z + xv.w * wv3.z;
            acc[i][3] += xv.x * wv0.w + xv.y * wv1.w + xv.z * wv2.w + xv.w * wv3.w;
        }
    }
    for (int k = KM4; k < K; k++) {
        float4 wv = *(const float4*)&Wg[k * 128 + c4];
#pragma unroll
        for (int i = 0; i < 8; i++) {
            float xv = xs[(r0 + i) * XP + k];
            acc[i][0] += xv * wv.x; acc[i][1] += xv * wv.y;
            acc[i][2] += xv * wv.z; acc[i][3] += xv * wv.w;
        }
    }
#pragma unroll
    for (int i = 0; i < 8; i++)
        *(float4*)&bufA[(row0 + r0 + i) * 128 + c4] =
            make_float4(acc[i][0], acc[i][1], acc[i][2], acc[i][3]);
}

// ============================================================================
// attn: VERBATIM restore of the measured-153µs kernel (dense Wm pitch 33,
// broadcast-scan max/den, FP-CAS scatter, wave-uniform-broadcast aggregation).
// ============================================================================
__global__ __launch_bounds__(256) void attn_kernel(
    float* bufA,
    const int* __restrict__ srcp, const int* __restrict__ dstp,
    const float* __restrict__ EA,
    const unsigned char* __restrict__ nmg,
    const float* __restrict__ stat,      // ve at [384:404]
    const float* __restrict__ as_, const float* __restrict__ ad_,
    const float* __restrict__ bb,
    float* sums)
{
    __shared__ float hs[32 * 132];
    __shared__ float Wm[2 * 32 * 33];    // [h][src][dst], padded
    __shared__ float alpha[256];         // [e][h]
    __shared__ float hsd[64], hdd[64], aself[64], mxS[64], denS[64], lsumS[64];
    __shared__ float red[512];
    __shared__ int   lseS[128], ldeS[128], lcntS[32], nmlS[32];

    int g = blockIdx.x, tid = threadIdx.x;
    long gb = (long)g * 4096;

    for (int i = tid; i < 1024; i += 256) {
        int r = i >> 5, dc = (i & 31) * 4;
        *(float4*)&hs[r * 132 + dc] = *(const float4*)&bufA[gb + i * 4];
    }
    for (int i = tid; i < 2112; i += 256) Wm[i] = 0.f;
    if (tid < 64) lsumS[tid] = 0.f;
    if (tid < 32) { lcntS[tid] = 0; nmlS[tid] = (int)nmg[g * 32 + tid]; }

    float ea0 = 0.f, ea1 = 0.f;
    int myls = 0, myld = 0, mymk = 0;
    if (tid < 128) {
        myls = srcp[g * 128 + tid] & 31;
        myld = dstp[g * 128 + tid] & 31;
        lseS[tid] = myls; ldeS[tid] = myld;
        const float* ep = EA + (long)(g * 128 + tid) * 10;
#pragma unroll
        for (int j = 0; j < 10; j++) { float v = ep[j]; ea0 += v * stat[384 + j]; ea1 += v * stat[394 + j]; }
    }
    __syncthreads();   // B1

    {   // node dots
        int node = tid >> 3, l8 = tid & 7;
        float s0 = 0, s1 = 0, d0 = 0, d1 = 0;
        for (int m = 0; m < 8; m++) {
            int c = l8 + 8 * m;
            float h0 = hs[node * 132 + c], h1 = hs[node * 132 + 64 + c];
            s0 += h0 * as_[c]; s1 += h1 * as_[64 + c];
            d0 += h0 * ad_[c]; d1 += h1 * ad_[64 + c];
        }
        s0 += __shfl_xor(s0, 4); s0 += __shfl_xor(s0, 2); s0 += __shfl_xor(s0, 1);
        s1 += __shfl_xor(s1, 4); s1 += __shfl_xor(s1, 2); s1 += __shfl_xor(s1, 1);
        d0 += __shfl_xor(d0, 4); d0 += __shfl_xor(d0, 2); d0 += __shfl_xor(d0, 1);
        d1 += __shfl_xor(d1, 4); d1 += __shfl_xor(d1, 2); d1 += __shfl_xor(d1, 1);
        if (l8 == 0) { hsd[node * 2] = s0; hsd[node * 2 + 1] = s1; hdd[node * 2] = d0; hdd[node * 2 + 1] = d1; }
    }
    if (tid < 128) {
        mymk = nmlS[myls] & nmlS[myld];
        if (mymk) {
            atomicAdd(&lsumS[myld * 2], ea0);
            atomicAdd(&lsumS[myld * 2 + 1], ea1);
            atomicAdd(&lcntS[myld], 1);
        }
    }
    __syncthreads();   // B2

    if (tid < 128) {
        float a0 = hsd[myls * 2] + hdd[myld * 2] + ea0;
        float a1 = hsd[myls * 2 + 1] + hdd[myld * 2 + 1] + ea1;
        alpha[tid * 2]     = mymk ? lrelu(a0) : -1e9f;
        alpha[tid * 2 + 1] = mymk ? lrelu(a1) : -1e9f;
    } else if (tid < 160) {
        int n = tid - 128;
        float c = (lcntS[n] > 0) ? (float)lcntS[n] : 1.f;
        float a0 = hsd[n * 2] + hdd[n * 2] + lsumS[n * 2] / c;
        float a1 = hsd[n * 2 + 1] + hdd[n * 2 + 1] + lsumS[n * 2 + 1] / c;
        aself[n * 2]     = nmlS[n] ? lrelu(a0) : -1e9f;
        aself[n * 2 + 1] = nmlS[n] ? lrelu(a1) : -1e9f;
    }
    __syncthreads();   // B3

    // segment max + denominator: 128 threads = (n, h, half)
    if (tid < 128) {
        int n = tid >> 2, h = (tid >> 1) & 1, hf = tid & 1;
        float av = aself[n * 2 + h];
        float m = av;
        for (int e = hf * 64; e < hf * 64 + 64; e++)
            if (ldeS[e] == n) m = fmaxf(m, alpha[e * 2 + h]);
        m = fmaxf(m, __shfl_xor(m, 1));
        float s = (hf == 0 && av > -1e8f) ? __expf(av - m) : 0.f;
        for (int e = hf * 64; e < hf * 64 + 64; e++)
            if (ldeS[e] == n) { float a = alpha[e * 2 + h]; if (a > -1e8f) s += __expf(a - m); }
        s += __shfl_xor(s, 1);
        if (hf == 0) { mxS[n * 2 + h] = m; denS[n * 2 + h] = fmaxf(s, 1e-16f); }
    }
    __syncthreads();   // B4

    // softmax weights -> dense Wm
    if (tid < 128) {
        if (mymk) {
            float w0 = __expf(alpha[tid * 2]     - mxS[myld * 2])     / denS[myld * 2];
            float w1 = __expf(alpha[tid * 2 + 1] - mxS[myld * 2 + 1]) / denS[myld * 2 + 1];
            atomicAdd(&Wm[myls * 33 + myld], w0);
            atomicAdd(&Wm[1056 + myls * 33 + myld], w1);
        }
    } else if (tid < 160) {
        int n = tid - 128;
        if (nmlS[n]) {
            float w0 = __expf(aself[n * 2]     - mxS[n * 2])     / denS[n * 2];
            float w1 = __expf(aself[n * 2 + 1] - mxS[n * 2 + 1]) / denS[n * 2 + 1];
            atomicAdd(&Wm[n * 33 + n], w0);
            atomicAdd(&Wm[1056 + n * 33 + n], w1);
        }
    }
    __syncthreads();   // B5

    // dense aggregation (regular 32-step loop) + bias + BN partials + writeback
    {
        int d = tid & 127, h = d >> 6, nb = tid >> 7;   // thread covers n = nb+2i
        const float* Wh = &Wm[h * 1056];
        float av[16];
#pragma unroll
        for (int i = 0; i < 16; i++) av[i] = 0.f;
        for (int s = 0; s < 32; s++) {
            float hv = hs[s * 132 + d];
            const float* wr = &Wh[s * 33 + nb];
#pragma unroll
            for (int i = 0; i < 16; i++) av[i] += wr[2 * i] * hv;
        }
        float bv = bb[d];
        float sp = 0.f, sq = 0.f;
#pragma unroll
        for (int i = 0; i < 16; i++) {
            int n = nb + 2 * i;
            float v = av[i] + bv;
            bufA[gb + n * 128 + d] = v;
            if (nmlS[n]) { sp += v; sq += v * v; }
        }
        red[tid] = sp; red[256 + tid] = sq;
    }
    __syncthreads();
    if (tid < 128) {
        atomicAdd(&sums[tid], red[tid] + red[tid + 128]);
        atomicAdd(&sums[128 + tid], red[256 + tid] + red[256 + tid + 128]);
    }
}

// ============================================================================
__global__ __launch_bounds__(128) void setup_kernel(
    float* sums, float* stat, const float* __restrict__ We, const float* __restrict__ ae)
{
    int t = threadIdx.x;
    sums[t] = 0.f; sums[128 + t] = 0.f;
    if (t < 20) {
        int h = t / 10, j = t - 10 * h;
        float s = 0.f;
        for (int c = 0; c < 64; c++) s += We[j * 128 + h * 64 + c] * ae[h * 64 + c];
        stat[384 + t] = s;
    }
}

__global__ __launch_bounds__(128) void finalize_kernel(
    float* sums, float n, const float* __restrict__ pw, float* stat,
    const float* __restrict__ Wen, const float* __restrict__ aen)
{
    int d = threadIdx.x;
    float mean = sums[d] / n;
    float var = sums[128 + d] / n - mean * mean;
    if (var < 0.f) var = 0.f;
    float rstd = rsqrtf(var + 1e-5f);
    float p = pw[d];
    float q = p * p;
#pragma unroll
    for (int o = 32; o >= 1; o >>= 1) q += __shfl_xor(q, o);
    __shared__ float w2[2];
    if ((d & 63) == 0) w2[d >> 6] = q;
    __syncthreads();
    float nrm = sqrtf(w2[0] + w2[1]);
    stat[d] = mean; stat[128 + d] = rstd; stat[256 + d] = p / nrm;
    if (d < 20) {
        int h = d / 10, j = d - 10 * h;
        float s = 0.f;
        for (int c = 0; c < 64; c++) s += Wen[j * 128 + h * 64 + c] * aen[h * 64 + c];
        stat[384 + d] = s;
    }
    sums[d] = 0.f; sums[128 + d] = 0.f;
}

// ============================================================================
// final: pool layer-2 output (K=25) + readout + MLP head
// ============================================================================
__global__ __launch_bounds__(256) void final_kernel(
    const float* __restrict__ bufA, const unsigned char* __restrict__ nmg,
    const float* __restrict__ stat,
    const float* __restrict__ gamma, const float* __restrict__ beta,
    const float* __restrict__ zacc,
    const float* __restrict__ fw1, const float* __restrict__ fb1,
    const float* __restrict__ fw2, const float* __restrict__ fb2,
    float* __restrict__ out)
{
    __shared__ float xs[32 * 132], zt[128], hred[64], scS[32], tsS[32];
    __shared__ int nmlS[32];
    int g = blockIdx.x, tid = threadIdx.x;
    long gb = (long)g * 4096;

    if (tid < 32) nmlS[tid] = (int)nmg[g * 32 + tid];
    for (int i = tid; i < 1024; i += 256) {
        int r = i >> 5, dc = (i & 31) * 4;
        float4 v = *(const float4*)&bufA[gb + i * 4];
        v.x = fmaxf(gamma[dc    ] * (v.x - stat[dc    ]) * stat[128 + dc    ] + beta[dc    ], 0.f);
        v.y = fmaxf(gamma[dc + 1] * (v.y - stat[dc + 1]) * stat[128 + dc + 1] + beta[dc + 1], 0.f);
        v.z = fmaxf(gamma[dc + 2] * (v.z - stat[dc + 2]) * stat[128 + dc + 2] + beta[dc + 2], 0.f);
        v.w = fmaxf(gamma[dc + 3] * (v.w - stat[dc + 3]) * stat[128 + dc + 3] + beta[dc + 3], 0.f);
        *(float4*)&xs[r * 132 + dc] = v;
    }
    __syncthreads();

    {
        int node = tid >> 3, l8 = tid & 7;
        float s = 0.f;
        for (int m = 0; m < 16; m++) { int c = l8 + 8 * m; s += xs[node * 132 + c] * stat[256 + c]; }
        s += __shfl_xor(s, 4); s += __shfl_xor(s, 2); s += __shfl_xor(s, 1);
        if (l8 == 0) scS[node] = s;
    }
    __syncthreads();

    if (tid < 32) {
        float sn = nmlS[tid] ? scS[tid] : -1e9f;
        int cnt = 0;
        for (int j = 0; j < 32; j++) {
            float sj = nmlS[j] ? scS[j] : -1e9f;
            cnt += (sj > sn || (sj == sn && j < tid)) ? 1 : 0;
        }
        tsS[tid] = (cnt < 25) ? tanhf(scS[tid]) : 0.f;
    }
    __syncthreads();

    if (tid < 128) {
        float s = 0.f;
        for (int n = 0; n < 32; n++) s += xs[n * 132 + tid] * tsS[n];
        zt[tid] = zacc[(long)g * 128 + tid] + s * (1.0f / 25.0f);
    }
    __syncthreads();

    {
        int j = tid >> 2, p = tid & 3;
        float s = 0.f;
        for (int d = p * 32; d < p * 32 + 32; d++) s += zt[d] * fw1[d * 64 + j];
        s += __shfl_xor(s, 1); s += __shfl_xor(s, 2);
        if (p == 0) hred[j] = fmaxf(s + fb1[j], 0.f) * fw2[j];
    }
    __syncthreads();
    if (tid < 64) {
        float v = hred[tid];
#pragma unroll
        for (int o = 32; o >= 1; o >>= 1) v += __shfl_xor(v, o);
        if (tid == 0) out[g] = v + fb2[0];
    }
}

extern "C" void kernel_launch(void* const* d_in, const int* in_sizes, int n_in,
                              void* d_out, int out_size, void* d_ws, size_t ws_size,
                              hipStream_t stream)
{
    const float* X0 = (const float*)d_in[0];
    const int*   EI = (const int*)d_in[1];
    const float* EA = (const float*)d_in[2];
    const int* srcp = EI;
    const int* dstp = EI + NE;

    const float* W1  = (const float*)d_in[4];  const float* We1 = (const float*)d_in[5];
    const float* as1 = (const float*)d_in[6];  const float* ad1 = (const float*)d_in[7];
    const float* ae1 = (const float*)d_in[8];  const float* b1  = (const float*)d_in[9];
    const float* g1  = (const float*)d_in[10]; const float* be1 = (const float*)d_in[11];
    const float* pw1 = (const float*)d_in[12];
    const float* W2  = (const float*)d_in[13]; const float* We2 = (const float*)d_in[14];
    const float* as2 = (const float*)d_in[15]; const float* ad2 = (const float*)d_in[16];
    const float* ae2 = (const float*)d_in[17]; const float* b2  = (const float*)d_in[18];
    const float* g2  = (const float*)d_in[19]; const float* be2 = (const float*)d_in[20];
    const float* pw2 = (const float*)d_in[21];
    const float* W3  = (const float*)d_in[22]; const float* We3 = (const float*)d_in[23];
    const float* as3 = (const float*)d_in[24]; const float* ad3 = (const float*)d_in[25];
    const float* ae3 = (const float*)d_in[26]; const float* b3  = (const float*)d_in[27];
    const float* g3  = (const float*)d_in[28]; const float* be3 = (const float*)d_in[29];
    const float* pw3 = (const float*)d_in[30];
    const float* fw1 = (const float*)d_in[31]; const float* fb1 = (const float*)d_in[32];
    const float* fw2 = (const float*)d_in[33]; const float* fb2 = (const float*)d_in[34];

    float* bufA = (float*)d_ws;                       // NN*128 f32
    float* z    = bufA + (size_t)NN * 128;            // NG*128 f32
    float* sums = z + (size_t)NG * 128;               // 256 f32
    float* stat = sums + 256;                         // 512 f32
    unsigned char* nmg = (unsigned char*)(stat + 512);// NG*32 bytes

    hipMemsetAsync(nmg, 1, NN, stream);
    hipMemsetAsync(z, 0, (size_t)NG * 128 * sizeof(float), stream);
    setup_kernel<<<1, 128, 0, stream>>>(sums, stat, We1, ae1);

    // layer 0
    pool_gemm_kernel<41, 0, 1><<<NN / 64, 256, 0, stream>>>(
        X0, bufA, nmg, stat, g1, be1, W1, z);
    attn_kernel<<<NG, 256, 0, stream>>>(bufA, srcp, dstp, EA, nmg, stat, as1, ad1, b1, sums);
    finalize_kernel<<<1, 128, 0, stream>>>(sums, 131072.f, pw1, stat, We2, ae2);

    // layer 1 (pools layer-0 output, K=29)
    pool_gemm_kernel<128, 1, 29><<<NN / 64, 256, 0, stream>>>(
        X0, bufA, nmg, stat, g1, be1, W2, z);
    attn_kernel<<<NG, 256, 0, stream>>>(bufA, srcp, dstp, EA, nmg, stat, as2, ad2, b2, sums);
    finalize_kernel<<<1, 128, 0, stream>>>(sums, 4096.f * 29.f, pw2, stat, We3, ae3);

    // layer 2 (pools layer-1 output, K=27)
    pool_gemm_kernel<128, 2, 27><<<NN / 64, 256, 0, stream>>>(
        X0, bufA, nmg, stat, g2, be2, W3, z);
    attn_kernel<<<NG, 256, 0, stream>>>(bufA, srcp, dstp, EA, nmg, stat, as3, ad3, b3, sums);
    finalize_kernel<<<1, 128, 0, stream>>>(sums, 4096.f * 27.f, pw3, stat, We3, ae3);

    // final: pool layer-2 output (K=25) + readout + head
    final_kernel<<<NG, 256, 0, stream>>>(
        bufA, nmg, stat, g3, be3, z, fw1, fb1, fw2, fb2, (float*)d_out);
}

// Round 10
// 730.010 us; speedup vs baseline: 2.3121x; 1.1042x over previous
//
#include <hip/hip_runtime.h>

#define NN 131072   // nodes
#define NG 4096     // graphs
#define NE 524288   // edges

__device__ __forceinline__ float lrelu(float a){ return a>=0.f ? a : 0.2f*a; }

// ============================================================================
// pool_gemm: [pool(prev layer)] -> H = X @ W   (2 graphs = 64 rows per block)
// W read directly from global (L2-hot) -> no barriers in GEMM loop.
// ============================================================================
template<int K, int PMODE, int KSEL>
__global__ __launch_bounds__(256) void pool_gemm_kernel(
    const float* __restrict__ Xin, float* bufA, unsigned char* nmg,
    const float* __restrict__ stat,    // [0:128] mean, [128:256] rstd, [256:384] pw/||pw||
    const float* __restrict__ gamma, const float* __restrict__ beta,
    const float* __restrict__ Wg,      // K x 128
    float* zacc)
{
    constexpr int XP = (K == 41) ? 44 : 132;   // padded LDS pitch (16B-aligned)
    __shared__ float xs[64 * XP];
    __shared__ float scS[64], tsS[64];
    __shared__ int   nmlS[64];

    int tid = threadIdx.x;
    long row0 = (long)blockIdx.x * 64;
    int g0 = blockIdx.x * 2;

    if (PMODE == 0) {
        for (int i = tid; i < 64 * 41; i += 256) {
            int r = i / 41, c = i - r * 41;
            xs[r * 44 + c] = Xin[row0 * 41 + i];
        }
    } else {
        for (int i = tid; i < 2048; i += 256) {
            int r = i >> 5, dc = (i & 31) * 4;
            float4 v = *(const float4*)&bufA[(row0 + r) * 128 + dc];
            v.x = fmaxf(gamma[dc    ] * (v.x - stat[dc    ]) * stat[128 + dc    ] + beta[dc    ], 0.f);
            v.y = fmaxf(gamma[dc + 1] * (v.y - stat[dc + 1]) * stat[128 + dc + 1] + beta[dc + 1], 0.f);
            v.z = fmaxf(gamma[dc + 2] * (v.z - stat[dc + 2]) * stat[128 + dc + 2] + beta[dc + 2], 0.f);
            v.w = fmaxf(gamma[dc + 3] * (v.w - stat[dc + 3]) * stat[128 + dc + 3] + beta[dc + 3], 0.f);
            *(float4*)&xs[r * XP + dc] = v;
        }
        if (tid < 64) nmlS[tid] = (PMODE == 1) ? 1 : (int)nmg[g0 * 32 + tid];
    }
    __syncthreads();

    if (PMODE > 0) {
        {   // pool scores
            int node = tid >> 2, l4 = tid & 3;
            float s = 0.f;
            for (int m = 0; m < 32; m++) { int c = l4 + 4 * m; s += xs[node * XP + c] * stat[256 + c]; }
            s += __shfl_xor(s, 2); s += __shfl_xor(s, 1);
            if (l4 == 0) scS[node] = s;
        }
        __syncthreads();
        if (tid < 64) {   // stable top-k (ties: lower index wins)
            int gp = tid >> 5, n = tid & 31;
            float sn = nmlS[tid] ? scS[tid] : -1e9f;
            int cnt = 0;
            for (int j = 0; j < 32; j++) {
                float sj = nmlS[gp * 32 + j] ? scS[gp * 32 + j] : -1e9f;
                cnt += (sj > sn || (sj == sn && j < n)) ? 1 : 0;
            }
            int sl = (cnt < KSEL) ? 1 : 0;
            nmg[g0 * 32 + tid] = (unsigned char)sl;
            tsS[tid] = sl ? tanhf(scS[tid]) : 0.f;
        }
        __syncthreads();
        for (int i = tid; i < 2048; i += 256) {   // gate
            int r = i >> 5, dc = (i & 31) * 4;
            float t = tsS[r];
            float4 v = *(const float4*)&xs[r * XP + dc];
            v.x *= t; v.y *= t; v.z *= t; v.w *= t;
            *(float4*)&xs[r * XP + dc] = v;
        }
        __syncthreads();
        {   // readout accumulation (block owns its 2 graphs)
            int gp = tid >> 7, d = tid & 127;
            float s = 0.f;
            for (int n = 0; n < 32; n++) s += xs[(gp * 32 + n) * XP + d];
            zacc[(long)(g0 + gp) * 128 + d] += s * (1.0f / (float)KSEL);
        }
        __syncthreads();
    }

    // ---- GEMM
    int r0 = (tid >> 5) * 8, c4 = (tid & 31) * 4;
    float acc[8][4];
#pragma unroll
    for (int i = 0; i < 8; i++)
#pragma unroll
        for (int j = 0; j < 4; j++) acc[i][j] = 0.f;

    constexpr int KM4 = (K / 4) * 4;
#pragma unroll 2
    for (int k0 = 0; k0 < KM4; k0 += 4) {
        float4 wv0 = *(const float4*)&Wg[(k0 + 0) * 128 + c4];
        float4 wv1 = *(const float4*)&Wg[(k0 + 1) * 128 + c4];
        float4 wv2 = *(const float4*)&Wg[(k0 + 2) * 128 + c4];
        float4 wv3 = *(const float4*)&Wg[(k0 + 3) * 128 + c4];
#pragma unroll
        for (int i = 0; i < 8; i++) {
            float4 xv = *(const float4*)&xs[(r0 + i) * XP + k0];
            acc[i][0] += xv.x * wv0.x + xv.y * wv1.x + xv.z * wv2.x + xv.w * wv3.x;
            acc[i][1] += xv.x * wv0.y + xv.y * wv1.y + xv.z * wv2.y + xv.w * wv3.y;
            acc[i][2] += xv.x * wv0.z + xv.y * wv1.z + xv.z * wv2.z + xv.w * wv3.z;
            acc[i][3] += xv.x * wv0.w + xv.y * wv1.w + xv.z * wv2.w + xv.w * wv3.w;
        }
    }
    for (int k = KM4; k < K; k++) {
        float4 wv = *(const float4*)&Wg[k * 128 + c4];
#pragma unroll
        for (int i = 0; i < 8; i++) {
            float xv = xs[(r0 + i) * XP + k];
            acc[i][0] += xv * wv.x; acc[i][1] += xv * wv.y;
            acc[i][2] += xv * wv.z; acc[i][3] += xv * wv.w;
        }
    }
#pragma unroll
    for (int i = 0; i < 8; i++)
        *(float4*)&bufA[(row0 + r0 + i) * 128 + c4] =
            make_float4(acc[i][0], acc[i][1], acc[i][2], acc[i][3]);
}

// ============================================================================
// attn: no-max softmax (exact: exp(a)/sum exp(a)), FP-CAS scatter into dense
// Wm (pitch 36), 1-wave column-sum for den, aggregation with wave-uniform
// ds_read_b128 on Wm + stride-1 b32 on hs + coalesced stores.
// ============================================================================
__global__ __launch_bounds__(256) void attn_kernel(
    float* bufA,
    const int* __restrict__ srcp, const int* __restrict__ dstp,
    const float* __restrict__ EA,
    const unsigned char* __restrict__ nmg,
    const float* __restrict__ stat,      // ve at [384:404]
    const float* __restrict__ as_, const float* __restrict__ ad_,
    const float* __restrict__ bb,
    float* sums)
{
    __shared__ float hs[32 * 132];       // 16.9 KB
    __shared__ float Wm[2 * 32 * 36];    // 9.2 KB, [h][src s][dst n], pitch 36
    __shared__ float hsd[64], hdd[64], lsumS[64], rdenS[64];
    __shared__ float red[512];
    __shared__ int   lcntS[32], nmlS[32];

    int g = blockIdx.x, tid = threadIdx.x;
    long gb = (long)g * 4096;

    // ---- B1: init + loads
    for (int i = tid; i < 2304; i += 256) Wm[i] = 0.f;
    if (tid < 64) lsumS[tid] = 0.f;
    if (tid >= 64 && tid < 96) { lcntS[tid - 64] = 0; nmlS[tid - 64] = (int)nmg[g * 32 + tid - 64]; }
    for (int i = tid; i < 1024; i += 256) {
        int r = i >> 5, dc = (i & 31) * 4;
        *(float4*)&hs[r * 132 + dc] = *(const float4*)&bufA[gb + i * 4];
    }
    float ea0 = 0.f, ea1 = 0.f;
    int myls = 0, myld = 0;
    if (tid < 128) {
        myls = srcp[g * 128 + tid] & 31;
        myld = dstp[g * 128 + tid] & 31;
        const float* ep = EA + (long)(g * 128 + tid) * 10;
#pragma unroll
        for (int j = 0; j < 10; j++) { float v = ep[j]; ea0 += v * stat[384 + j]; ea1 += v * stat[394 + j]; }
    }
    __syncthreads();   // B1

    // ---- B2: node dots + loop-attr sums
    {
        int node = tid >> 3, l8 = tid & 7;
        float s0 = 0, s1 = 0, d0 = 0, d1 = 0;
        for (int m = 0; m < 8; m++) {
            int c = l8 + 8 * m;
            float h0 = hs[node * 132 + c], h1 = hs[node * 132 + 64 + c];
            s0 += h0 * as_[c]; s1 += h1 * as_[64 + c];
            d0 += h0 * ad_[c]; d1 += h1 * ad_[64 + c];
        }
        s0 += __shfl_xor(s0, 4); s0 += __shfl_xor(s0, 2); s0 += __shfl_xor(s0, 1);
        s1 += __shfl_xor(s1, 4); s1 += __shfl_xor(s1, 2); s1 += __shfl_xor(s1, 1);
        d0 += __shfl_xor(d0, 4); d0 += __shfl_xor(d0, 2); d0 += __shfl_xor(d0, 1);
        d1 += __shfl_xor(d1, 4); d1 += __shfl_xor(d1, 2); d1 += __shfl_xor(d1, 1);
        if (l8 == 0) { hsd[node * 2] = s0; hsd[node * 2 + 1] = s1; hdd[node * 2] = d0; hdd[node * 2 + 1] = d1; }
    }
    int mymk = 0;
    if (tid < 128) {
        mymk = nmlS[myls] & nmlS[myld];
        if (mymk) {
            atomicAdd(&lsumS[myld * 2], ea0);
            atomicAdd(&lsumS[myld * 2 + 1], ea1);
            atomicAdd(&lcntS[myld], 1);
        }
    }
    __syncthreads();   // B2

    // ---- B3: exp(alpha) scatter into Wm (edges + self-loops; no max-sub)
    if (tid < 128) {
        if (mymk) {
            float p0 = __expf(lrelu(hsd[myls * 2]     + hdd[myld * 2]     + ea0));
            float p1 = __expf(lrelu(hsd[myls * 2 + 1] + hdd[myld * 2 + 1] + ea1));
            atomicAdd(&Wm[myls * 36 + myld], p0);
            atomicAdd(&Wm[1152 + myls * 36 + myld], p1);
        }
    } else if (tid < 192) {
        int n = (tid - 128) >> 1, h = (tid - 128) & 1;
        if (nmlS[n]) {
            float c = (lcntS[n] > 0) ? (float)lcntS[n] : 1.f;
            float ps = __expf(lrelu(hsd[n * 2 + h] + hdd[n * 2 + h] + lsumS[n * 2 + h] / c));
            atomicAdd(&Wm[h * 1152 + n * 36 + n], ps);
        }
    }
    __syncthreads();   // B3

    // ---- B4: den = column sums of Wm (1 wave, 2-way-conflict-free)
    if (tid < 64) {
        int n = tid & 31, h = tid >> 5;
        const float* Wh = &Wm[h * 1152 + n];
        float den = 0.f;
#pragma unroll 8
        for (int s = 0; s < 32; s++) den += Wh[s * 36];
        rdenS[h * 32 + n] = 1.f / fmaxf(den, 1e-16f);
    }
    __syncthreads();   // B4

    // ---- agg: O[n,d] = (1/den[n]) * sum_s Wm[s,n]*hs[s,d] + b[d]
    {
        int d = tid & 127, h = d >> 6, nb = tid >> 7;   // n = nb*16 + i (contiguous)
        const float* Wh = &Wm[h * 1152 + nb * 16];
        float acc[16];
#pragma unroll
        for (int i = 0; i < 16; i++) acc[i] = 0.f;
        for (int s = 0; s < 32; s++) {
            float hv = hs[s * 132 + d];
            float4 w0 = *(const float4*)&Wh[s * 36];
            float4 w1 = *(const float4*)&Wh[s * 36 + 4];
            float4 w2 = *(const float4*)&Wh[s * 36 + 8];
            float4 w3 = *(const float4*)&Wh[s * 36 + 12];
            acc[0]  += w0.x * hv; acc[1]  += w0.y * hv; acc[2]  += w0.z * hv; acc[3]  += w0.w * hv;
            acc[4]  += w1.x * hv; acc[5]  += w1.y * hv; acc[6]  += w1.z * hv; acc[7]  += w1.w * hv;
            acc[8]  += w2.x * hv; acc[9]  += w2.y * hv; acc[10] += w2.z * hv; acc[11] += w2.w * hv;
            acc[12] += w3.x * hv; acc[13] += w3.y * hv; acc[14] += w3.z * hv; acc[15] += w3.w * hv;
        }
        float bv = bb[d];
        float sp = 0.f, sq = 0.f;
#pragma unroll
        for (int i = 0; i < 16; i++) {
            int n = nb * 16 + i;
            float v = acc[i] * rdenS[h * 32 + n] + bv;
            bufA[gb + n * 128 + d] = v;
            if (nmlS[n]) { sp += v; sq += v * v; }
        }
        red[tid] = sp; red[256 + tid] = sq;
    }
    __syncthreads();
    if (tid < 128) {
        atomicAdd(&sums[tid], red[tid] + red[tid + 128]);
        atomicAdd(&sums[128 + tid], red[256 + tid] + red[256 + tid + 128]);
    }
}

// ============================================================================
__global__ __launch_bounds__(128) void setup_kernel(
    float* sums, float* stat, const float* __restrict__ We, const float* __restrict__ ae)
{
    int t = threadIdx.x;
    sums[t] = 0.f; sums[128 + t] = 0.f;
    if (t < 20) {
        int h = t / 10, j = t - 10 * h;
        float s = 0.f;
        for (int c = 0; c < 64; c++) s += We[j * 128 + h * 64 + c] * ae[h * 64 + c];
        stat[384 + t] = s;
    }
}

__global__ __launch_bounds__(128) void finalize_kernel(
    float* sums, float n, const float* __restrict__ pw, float* stat,
    const float* __restrict__ Wen, const float* __restrict__ aen)
{
    int d = threadIdx.x;
    float mean = sums[d] / n;
    float var = sums[128 + d] / n - mean * mean;
    if (var < 0.f) var = 0.f;
    float rstd = rsqrtf(var + 1e-5f);
    float p = pw[d];
    float q = p * p;
#pragma unroll
    for (int o = 32; o >= 1; o >>= 1) q += __shfl_xor(q, o);
    __shared__ float w2[2];
    if ((d & 63) == 0) w2[d >> 6] = q;
    __syncthreads();
    float nrm = sqrtf(w2[0] + w2[1]);
    stat[d] = mean; stat[128 + d] = rstd; stat[256 + d] = p / nrm;
    if (d < 20) {
        int h = d / 10, j = d - 10 * h;
        float s = 0.f;
        for (int c = 0; c < 64; c++) s += Wen[j * 128 + h * 64 + c] * aen[h * 64 + c];
        stat[384 + d] = s;
    }
    sums[d] = 0.f; sums[128 + d] = 0.f;
}

// ============================================================================
// final: pool layer-2 output (K=25) + readout + MLP head
// ============================================================================
__global__ __launch_bounds__(256) void final_kernel(
    const float* __restrict__ bufA, const unsigned char* __restrict__ nmg,
    const float* __restrict__ stat,
    const float* __restrict__ gamma, const float* __restrict__ beta,
    const float* __restrict__ zacc,
    const float* __restrict__ fw1, const float* __restrict__ fb1,
    const float* __restrict__ fw2, const float* __restrict__ fb2,
    float* __restrict__ out)
{
    __shared__ float xs[32 * 132], zt[128], hred[64], scS[32], tsS[32];
    __shared__ int nmlS[32];
    int g = blockIdx.x, tid = threadIdx.x;
    long gb = (long)g * 4096;

    if (tid < 32) nmlS[tid] = (int)nmg[g * 32 + tid];
    for (int i = tid; i < 1024; i += 256) {
        int r = i >> 5, dc = (i & 31) * 4;
        float4 v = *(const float4*)&bufA[gb + i * 4];
        v.x = fmaxf(gamma[dc    ] * (v.x - stat[dc    ]) * stat[128 + dc    ] + beta[dc    ], 0.f);
        v.y = fmaxf(gamma[dc + 1] * (v.y - stat[dc + 1]) * stat[128 + dc + 1] + beta[dc + 1], 0.f);
        v.z = fmaxf(gamma[dc + 2] * (v.z - stat[dc + 2]) * stat[128 + dc + 2] + beta[dc + 2], 0.f);
        v.w = fmaxf(gamma[dc + 3] * (v.w - stat[dc + 3]) * stat[128 + dc + 3] + beta[dc + 3], 0.f);
        *(float4*)&xs[r * 132 + dc] = v;
    }
    __syncthreads();

    {
        int node = tid >> 3, l8 = tid & 7;
        float s = 0.f;
        for (int m = 0; m < 16; m++) { int c = l8 + 8 * m; s += xs[node * 132 + c] * stat[256 + c]; }
        s += __shfl_xor(s, 4); s += __shfl_xor(s, 2); s += __shfl_xor(s, 1);
        if (l8 == 0) scS[node] = s;
    }
    __syncthreads();

    if (tid < 32) {
        float sn = nmlS[tid] ? scS[tid] : -1e9f;
        int cnt = 0;
        for (int j = 0; j < 32; j++) {
            float sj = nmlS[j] ? scS[j] : -1e9f;
            cnt += (sj > sn || (sj == sn && j < tid)) ? 1 : 0;
        }
        tsS[tid] = (cnt < 25) ? tanhf(scS[tid]) : 0.f;
    }
    __syncthreads();

    if (tid < 128) {
        float s = 0.f;
        for (int n = 0; n < 32; n++) s += xs[n * 132 + tid] * tsS[n];
        zt[tid] = zacc[(long)g * 128 + tid] + s * (1.0f / 25.0f);
    }
    __syncthreads();

    {
        int j = tid >> 2, p = tid & 3;
        float s = 0.f;
        for (int d = p * 32; d < p * 32 + 32; d++) s += zt[d] * fw1[d * 64 + j];
        s += __shfl_xor(s, 1); s += __shfl_xor(s, 2);
        if (p == 0) hred[j] = fmaxf(s + fb1[j], 0.f) * fw2[j];
    }
    __syncthreads();
    if (tid < 64) {
        float v = hred[tid];
#pragma unroll
        for (int o = 32; o >= 1; o >>= 1) v += __shfl_xor(v, o);
        if (tid == 0) out[g] = v + fb2[0];
    }
}

extern "C" void kernel_launch(void* const* d_in, const int* in_sizes, int n_in,
                              void* d_out, int out_size, void* d_ws, size_t ws_size,
                              hipStream_t stream)
{
    const float* X0 = (const float*)d_in[0];
    const int*   EI = (const int*)d_in[1];
    const float* EA = (const float*)d_in[2];
    const int* srcp = EI;
    const int* dstp = EI + NE;

    const float* W1  = (const float*)d_in[4];  const float* We1 = (const float*)d_in[5];
    const float* as1 = (const float*)d_in[6];  const float* ad1 = (const float*)d_in[7];
    const float* ae1 = (const float*)d_in[8];  const float* b1  = (const float*)d_in[9];
    const float* g1  = (const float*)d_in[10]; const float* be1 = (const float*)d_in[11];
    const float* pw1 = (const float*)d_in[12];
    const float* W2  = (const float*)d_in[13]; const float* We2 = (const float*)d_in[14];
    const float* as2 = (const float*)d_in[15]; const float* ad2 = (const float*)d_in[16];
    const float* ae2 = (const float*)d_in[17]; const float* b2  = (const float*)d_in[18];
    const float* g2  = (const float*)d_in[19]; const float* be2 = (const float*)d_in[20];
    const float* pw2 = (const float*)d_in[21];
    const float* W3  = (const float*)d_in[22]; const float* We3 = (const float*)d_in[23];
    const float* as3 = (const float*)d_in[24]; const float* ad3 = (const float*)d_in[25];
    const float* ae3 = (const float*)d_in[26]; const float* b3  = (const float*)d_in[27];
    const float* g3  = (const float*)d_in[28]; const float* be3 = (const float*)d_in[29];
    const float* pw3 = (const float*)d_in[30];
    const float* fw1 = (const float*)d_in[31]; const float* fb1 = (const float*)d_in[32];
    const float* fw2 = (const float*)d_in[33]; const float* fb2 = (const float*)d_in[34];

    float* bufA = (float*)d_ws;                       // NN*128 f32
    float* z    = bufA + (size_t)NN * 128;            // NG*128 f32
    float* sums = z + (size_t)NG * 128;               // 256 f32
    float* stat = sums + 256;                         // 512 f32
    unsigned char* nmg = (unsigned char*)(stat + 512);// NG*32 bytes

    hipMemsetAsync(nmg, 1, NN, stream);
    hipMemsetAsync(z, 0, (size_t)NG * 128 * sizeof(float), stream);
    setup_kernel<<<1, 128, 0, stream>>>(sums, stat, We1, ae1);

    // layer 0
    pool_gemm_kernel<41, 0, 1><<<NN / 64, 256, 0, stream>>>(
        X0, bufA, nmg, stat, g1, be1, W1, z);
    attn_kernel<<<NG, 256, 0, stream>>>(bufA, srcp, dstp, EA, nmg, stat, as1, ad1, b1, sums);
    finalize_kernel<<<1, 128, 0, stream>>>(sums, 131072.f, pw1, stat, We2, ae2);

    // layer 1 (pools layer-0 output, K=29)
    pool_gemm_kernel<128, 1, 29><<<NN / 64, 256, 0, stream>>>(
        X0, bufA, nmg, stat, g1, be1, W2, z);
    attn_kernel<<<NG, 256, 0, stream>>>(bufA, srcp, dstp, EA, nmg, stat, as2, ad2, b2, sums);
    finalize_kernel<<<1, 128, 0, stream>>>(sums, 4096.f * 29.f, pw2, stat, We3, ae3);

    // layer 2 (pools layer-1 output, K=27)
    pool_gemm_kernel<128, 2, 27><<<NN / 64, 256, 0, stream>>>(
        X0, bufA, nmg, stat, g2, be2, W3, z);
    attn_kernel<<<NG, 256, 0, stream>>>(bufA, srcp, dstp, EA, nmg, stat, as3, ad3, b3, sums);
    finalize_kernel<<<1, 128, 0, stream>>>(sums, 4096.f * 27.f, pw3, stat, We3, ae3);

    // final: pool layer-2 output (K=25) + readout + head
    final_kernel<<<NG, 256, 0, stream>>>(
        bufA, nmg, stat, g3, be3, z, fw1, fb1, fw2, fb2, (float*)d_out);
}